// Round 1
// baseline (303.210 us; speedup 1.0000x reference)
//
#include <hip/hip_runtime.h>
#include <math.h>

// Problem constants
#define BATCH 8
#define NNODE 512
#define BN 4096           // BATCH*NNODE
#define DIM 128
#define HID 64
#define CAP 64            // max neighbors per row (mean ~20, 10 sigma margin)

// ---------------------------------------------------------------------------
// K0: zero loss accumulator + compute c1 = scalar weight-MLP(1.0)
// weights = weight_mlp(A)*A == c1*A since A is exactly {0,1}
// ---------------------------------------------------------------------------
__global__ __launch_bounds__(64) void k_init(
    const float* wm_W1, const float* wm_b1, const float* wm_W2,
    const float* wm_b2, const float* wm_W3, const float* wm_b3,
    float* c1_out, float* loss_acc) {
  __shared__ float xs[64];
  __shared__ float ys[32];
  int l = threadIdx.x;
  if (l == 0) *loss_acc = 0.f;
  xs[l] = fmaxf(0.f, wm_W1[l] + wm_b1[l]);   // relu(1*W1[0]+b1)
  __syncthreads();
  if (l < 32) {
    float acc = wm_b2[l];
    for (int k = 0; k < 64; k++) acc += xs[k] * wm_W2[k * 32 + l];
    ys[l] = fmaxf(0.f, acc);
  }
  __syncthreads();
  if (l == 0) {
    float acc = wm_b3[0];
    for (int k = 0; k < 32; k++) acc += ys[k] * wm_W3[k];
    *c1_out = 1.f / (1.f + expf(-acc));
  }
}

// ---------------------------------------------------------------------------
// K1: per-node MLPs: kappa (curv weights) and f_i (fn weights, i=0..2)
// block = 256 threads = 4 waves = 4 nodes; W1 staged in LDS per MLP
// ---------------------------------------------------------------------------
__global__ __launch_bounds__(256) void k_node_mlps(
    const float* X, const float* cW1, const float* cb1, const float* cW2,
    const float* cb2, const float* fW1, const float* fb1, const float* fW2,
    const float* fb2, float* kap, float* f) {
  __shared__ float W1s[DIM * HID];
  __shared__ float xs[4][DIM];
  int tid = threadIdx.x;
  int wave = tid >> 6, lane = tid & 63;
  int node0 = blockIdx.x * 4;
  for (int t = tid; t < 4 * DIM; t += 256)
    xs[t >> 7][t & 127] = X[(size_t)node0 * DIM + t];
  for (int m = 0; m < 4; m++) {
    const float* W1 = (m == 0) ? cW1 : fW1 + (size_t)(m - 1) * DIM * HID;
    __syncthreads();
    for (int t = tid; t < DIM * HID; t += 256) W1s[t] = W1[t];
    __syncthreads();
    const float* b1 = (m == 0) ? cb1 : fb1 + (m - 1) * HID;
    const float* W2 = (m == 0) ? cW2 : fW2 + (m - 1) * HID;
    float b2v = (m == 0) ? cb2[0] : fb2[m - 1];
    float acc = b1[lane];
    const float* xv = xs[wave];
    for (int k = 0; k < DIM; k++) acc += xv[k] * W1s[k * HID + lane];
    float part = fmaxf(0.f, acc) * W2[lane];
    for (int off = 32; off; off >>= 1) part += __shfl_down(part, off, 64);
    if (lane == 0) {
      float s = 1.f / (1.f + expf(-(part + b2v)));
      int node = node0 + wave;
      if (m == 0) kap[node] = s;
      else f[node * 3 + (m - 1)] = s;
    }
  }
}

// ---------------------------------------------------------------------------
// K2: per-batch top-k masks via rank counting (ties -> lower index wins,
// matching jax.lax.top_k).  M1 = prune mask at t=0 (num1), M2 = cumulative
// mask after t=1 (num1 AND num2).
// ---------------------------------------------------------------------------
__global__ __launch_bounds__(512) void k_masks(const float* kap,
                                               const int* p_ptr, float* M1,
                                               float* M2) {
  int b = blockIdx.x;
  int i = threadIdx.x;
  __shared__ float ks[NNODE];
  ks[i] = kap[b * NNODE + i];
  __syncthreads();
  float v = ks[i];
  int rank = 0;
  for (int j = 0; j < NNODE; j++) {
    float u = ks[j];
    rank += (u > v) || (u == v && j < i);
  }
  int p = *p_ptr;
  int num1 = (NNODE * p) / 100;        // int(512*10/100) = 51
  int num2 = (NNODE * 2 * p) / 100;    // int(512*20/100) = 102
  float m1 = (rank < num1) ? 0.f : 1.f;
  float m2 = (rank < num1 || rank < num2) ? 0.f : 1.f;
  M1[b * NNODE + i] = m1;
  M2[b * NNODE + i] = m2;
}

// ---------------------------------------------------------------------------
// K3: build CSR neighbor lists from binary A, plus exact row degree.
// one wave per row.
// ---------------------------------------------------------------------------
__global__ __launch_bounds__(64) void k_csr(const float* A, int* csr,
                                            int* cnt_arr, float* deg) {
  int r = blockIdx.x;
  int lane = threadIdx.x;
  const float* row = A + (size_t)r * NNODE;
  int base = r * CAP;
  int cnt = 0;
  for (int c = 0; c < NNODE / 64; c++) {
    int j = c * 64 + lane;
    float a = row[j];
    bool nz = (a != 0.f);
    unsigned long long m = __ballot(nz);
    if (nz) {
      int pos = __popcll(m & ((1ull << lane) - 1ull));
      int slot = cnt + pos;
      if (slot < CAP) csr[base + slot] = j;
    }
    cnt += (int)__popcll(m);
  }
  if (lane == 0) {
    cnt_arr[r] = cnt < CAP ? cnt : CAP;
    deg[r] = (float)cnt;
  }
}

// ---------------------------------------------------------------------------
// K4: curvature pass1: per row, s1_i = sum_nbr f_i[j], s2_i = sum_nbr f_i[j]^2
// ---------------------------------------------------------------------------
__global__ __launch_bounds__(256) void k_pass1(const float* f, const int* csr,
                                               const int* cnt, float* P1) {
  int r = blockIdx.x * blockDim.x + threadIdx.x;
  if (r >= BN) return;
  int b = r >> 9;
  const int* nb = csr + r * CAP;
  int n = cnt[r];
  float s[6] = {0, 0, 0, 0, 0, 0};
  for (int t = 0; t < n; t++) {
    int j = nb[t];
    const float* fj = f + (size_t)((b << 9) + j) * 3;
    float f0 = fj[0], f1 = fj[1], f2 = fj[2];
    s[0] += f0; s[1] += f1; s[2] += f2;
    s[3] += f0 * f0; s[4] += f1 * f1; s[5] += f2 * f2;
  }
  float* o = P1 + r * 6;
  for (int c = 0; c < 6; c++) o[c] = s[c];
}

// ---------------------------------------------------------------------------
// K5: elementwise gamma, delta_f, f*delta_f  (w = c1*A)
// ---------------------------------------------------------------------------
__global__ __launch_bounds__(256) void k_gamma(const float* f, const float* deg,
                                               const float* P1,
                                               const float* c1p, float* G) {
  int r = blockIdx.x * blockDim.x + threadIdx.x;
  if (r >= BN) return;
  float c1 = *c1p;
  float dA = deg[r];
  for (int i = 0; i < 3; i++) {
    float fi = f[r * 3 + i];
    float s1 = P1[r * 6 + i];
    float s2 = P1[r * 6 + 3 + i];
    float gamma = 0.5f * c1 * (fi * fi * dA - 2.f * fi * s1 + s2);
    float df = c1 * (fi * dA - s1);
    G[r * 9 + i * 3 + 0] = gamma;
    G[r * 9 + i * 3 + 1] = df;
    G[r * 9 + i * 3 + 2] = fi * df;
  }
}

// ---------------------------------------------------------------------------
// K6: curvature pass2 gather + loss:  per row gather A@[gamma,df,f*df] then
// delta_gamma, gfd, gamma2, relu(kap*gamma - gamma2); fold in -3*kap.
// ---------------------------------------------------------------------------
__global__ __launch_bounds__(256) void k_pass2(
    const float* f, const float* kap, const float* deg, const float* P1,
    const float* G, const int* csr, const int* cnt, const float* c1p,
    float* loss_acc) {
  int r = blockIdx.x * blockDim.x + threadIdx.x;
  float local = 0.f;
  if (r < BN) {
    int b = r >> 9;
    const int* nb = csr + r * CAP;
    int n = cnt[r];
    float T[9] = {0, 0, 0, 0, 0, 0, 0, 0, 0};
    for (int t = 0; t < n; t++) {
      int j = nb[t];
      const float* g = G + (size_t)((b << 9) + j) * 9;
      for (int c = 0; c < 9; c++) T[c] += g[c];
    }
    float c1 = *c1p;
    float dA = deg[r];
    float kp = kap[r];
    for (int i = 0; i < 3; i++) {
      float fi = f[r * 3 + i];
      float s1 = P1[r * 6 + i];
      float gamma = G[r * 9 + i * 3 + 0];
      float df = G[r * 9 + i * 3 + 1];
      float Tg = T[i * 3 + 0], Tdf = T[i * 3 + 1], Tfdf = T[i * 3 + 2];
      float dgamma = c1 * (gamma * dA - Tg);
      float gfd = 0.5f * c1 * (fi * df * dA - fi * Tdf - df * s1 + Tfdf);
      float gamma2 = 0.5f * dgamma - gfd;
      local += fmaxf(0.f, kp * gamma - gamma2);
    }
    local -= 3.f * kp;   // the "- kappa.sum()" term, once per f_i
  }
  for (int off = 32; off; off >>= 1) local += __shfl_down(local, off, 64);
  if ((threadIdx.x & 63) == 0) atomicAdd(loss_acc, local);
}

// ---------------------------------------------------------------------------
// GIN layer: agg = (1+eps)*h + M[i]*sum_{j in nbr, M[j]} h[j];
// h' = relu(relu(agg@W1+b1)@W2+b2).  4 rows per 256-thread block, weights in LDS.
// ---------------------------------------------------------------------------
template <int CIN>
__global__ __launch_bounds__(256) void k_gin(
    const float* hin, const float* W1, const float* b1, const float* W2,
    const float* b2, const float* eps_arr, int eps_idx, const int* csr,
    const int* cnt, const float* mask, float* hout) {
  __shared__ float W1s[CIN * HID];
  __shared__ float W2s[HID * HID];
  __shared__ float aggs[4][CIN];
  __shared__ float zs[4][HID];
  int tid = threadIdx.x;
  int wave = tid >> 6, lane = tid & 63;
  int r = blockIdx.x * 4 + wave;
  int b = r >> 9;
  for (int t = tid; t < CIN * HID; t += 256) W1s[t] = W1[t];
  for (int t = tid; t < HID * HID; t += 256) W2s[t] = W2[t];
  float eps1 = 1.f + eps_arr[eps_idx];
  const float* hi = hin + (size_t)r * CIN;
  float a0 = eps1 * hi[lane];
  float a1 = (CIN == 128) ? eps1 * hi[lane + 64] : 0.f;
  bool rowon = (mask == nullptr) || (mask[r] != 0.f);
  if (rowon) {
    int n = cnt[r];
    const int* nb = csr + r * CAP;
    for (int t = 0; t < n; t++) {
      int j = nb[t];
      int rj = (b << 9) + j;
      if (mask && mask[rj] == 0.f) continue;
      const float* hj = hin + (size_t)rj * CIN;
      a0 += hj[lane];
      if (CIN == 128) a1 += hj[lane + 64];
    }
  }
  aggs[wave][lane] = a0;
  if (CIN == 128) aggs[wave][lane + 64] = a1;
  __syncthreads();
  float acc = b1[lane];
  const float* av = aggs[wave];
  for (int k = 0; k < CIN; k++) acc += av[k] * W1s[k * HID + lane];
  zs[wave][lane] = fmaxf(0.f, acc);
  __syncthreads();
  float acc2 = b2[lane];
  const float* zv = zs[wave];
  for (int k = 0; k < HID; k++) acc2 += zv[k] * W2s[k * HID + lane];
  hout[(size_t)r * HID + lane] = fmaxf(0.f, acc2);
}

// ---------------------------------------------------------------------------
// K10: feature sums over N, output GEMM [8,320]@[320,10]+b, write curv_loss.
// ---------------------------------------------------------------------------
__global__ __launch_bounds__(320) void k_out(
    const float* X, const float* h1, const float* h2, const float* h3,
    const float* out_W, const float* out_b, const float* loss_acc,
    float* out) {
  int b = blockIdx.x;
  int t = threadIdx.x;  // 320
  __shared__ float S[320];
  const float* src;
  int C, col;
  if (t < 128)      { src = X  + (size_t)b * NNODE * DIM; C = DIM; col = t; }
  else if (t < 192) { src = h1 + (size_t)b * NNODE * HID; C = HID; col = t - 128; }
  else if (t < 256) { src = h2 + (size_t)b * NNODE * HID; C = HID; col = t - 192; }
  else              { src = h3 + (size_t)b * NNODE * HID; C = HID; col = t - 256; }
  float s = 0.f;
  for (int n = 0; n < NNODE; n++) s += src[(size_t)n * C + col];
  S[t] = s;
  __syncthreads();
  if (t < 10) {
    float acc = out_b[t];
    for (int d = 0; d < 320; d++) acc += S[d] * out_W[d * 10 + t];
    out[b * 10 + t] = acc;
  }
  if (b == 0 && t == 0) out[80] = *loss_acc;
}

// ---------------------------------------------------------------------------
extern "C" void kernel_launch(void* const* d_in, const int* in_sizes, int n_in,
                              void* d_out, int out_size, void* d_ws,
                              size_t ws_size, hipStream_t stream) {
  const float* X       = (const float*)d_in[0];
  const float* A       = (const float*)d_in[1];
  const int*   p       = (const int*)d_in[2];
  const float* curv_W1 = (const float*)d_in[3];
  const float* curv_b1 = (const float*)d_in[4];
  const float* curv_W2 = (const float*)d_in[5];
  const float* curv_b2 = (const float*)d_in[6];
  const float* wm_W1   = (const float*)d_in[7];
  const float* wm_b1   = (const float*)d_in[8];
  const float* wm_W2   = (const float*)d_in[9];
  const float* wm_b2   = (const float*)d_in[10];
  const float* wm_W3   = (const float*)d_in[11];
  const float* wm_b3   = (const float*)d_in[12];
  const float* fn_W1   = (const float*)d_in[13];
  const float* fn_b1   = (const float*)d_in[14];
  const float* fn_W2   = (const float*)d_in[15];
  const float* fn_b2   = (const float*)d_in[16];
  const float* gin_eps = (const float*)d_in[17];
  const float* g0_W1   = (const float*)d_in[18];
  const float* g0_b1   = (const float*)d_in[19];
  const float* g0_W2   = (const float*)d_in[20];
  const float* g0_b2   = (const float*)d_in[21];
  const float* g1_W1   = (const float*)d_in[22];
  const float* g1_b1   = (const float*)d_in[23];
  const float* g1_W2   = (const float*)d_in[24];
  const float* g1_b2   = (const float*)d_in[25];
  const float* g2_W1   = (const float*)d_in[26];
  const float* g2_b1   = (const float*)d_in[27];
  const float* g2_W2   = (const float*)d_in[28];
  const float* g2_b2   = (const float*)d_in[29];
  const float* out_W   = (const float*)d_in[30];
  const float* out_b   = (const float*)d_in[31];
  float* out = (float*)d_out;

  float* ws = (float*)d_ws;
  size_t o = 0;
  float* loss_acc = ws + o; o += 16;          // padded
  float* c1       = ws + o; o += 16;
  float* kap      = ws + o; o += BN;
  float* f        = ws + o; o += (size_t)BN * 3;
  float* deg      = ws + o; o += BN;
  float* M1       = ws + o; o += BN;
  float* M2       = ws + o; o += BN;
  float* P1       = ws + o; o += (size_t)BN * 6;
  float* G        = ws + o; o += (size_t)BN * 9;
  float* h1       = ws + o; o += (size_t)BN * HID;
  float* h2       = ws + o; o += (size_t)BN * HID;
  float* h3       = ws + o; o += (size_t)BN * HID;
  int* cnt = (int*)(ws + o); o += BN;
  int* csr = (int*)(ws + o); o += (size_t)BN * CAP;

  k_init<<<1, 64, 0, stream>>>(wm_W1, wm_b1, wm_W2, wm_b2, wm_W3, wm_b3, c1,
                               loss_acc);
  k_node_mlps<<<BN / 4, 256, 0, stream>>>(X, curv_W1, curv_b1, curv_W2,
                                          curv_b2, fn_W1, fn_b1, fn_W2, fn_b2,
                                          kap, f);
  k_masks<<<BATCH, NNODE, 0, stream>>>(kap, p, M1, M2);
  k_csr<<<BN, 64, 0, stream>>>(A, csr, cnt, deg);
  k_pass1<<<BN / 256, 256, 0, stream>>>(f, csr, cnt, P1);
  k_gamma<<<BN / 256, 256, 0, stream>>>(f, deg, P1, c1, G);
  k_pass2<<<BN / 256, 256, 0, stream>>>(f, kap, deg, P1, G, csr, cnt, c1,
                                        loss_acc);
  k_gin<128><<<BN / 4, 256, 0, stream>>>(X, g0_W1, g0_b1, g0_W2, g0_b2,
                                         gin_eps, 0, csr, cnt, nullptr, h1);
  k_gin<64><<<BN / 4, 256, 0, stream>>>(h1, g1_W1, g1_b1, g1_W2, g1_b2,
                                        gin_eps, 1, csr, cnt, M1, h2);
  k_gin<64><<<BN / 4, 256, 0, stream>>>(h2, g2_W1, g2_b1, g2_W2, g2_b2,
                                        gin_eps, 2, csr, cnt, M2, h3);
  k_out<<<BATCH, 320, 0, stream>>>(X, h1, h2, h3, out_W, out_b, loss_acc, out);
}